// Round 8
// baseline (185.047 us; speedup 1.0000x reference)
//
#include <hip/hip_runtime.h>
#include <math.h>

#define NB 32
#define NN 262144
#define NG 256
#define NC 128            // chunks per batch (sort passes)
#define CH (NN/NC)        // 2048 elements per chunk
#define SC (CH/4)         // 512 elements per wave (4 waves/block)
#define CD 64             // chunks per batch, apply pass
#define ELD (NN/CD)       // 4096 elements per apply block

// ---------------- Pass 1: per-(batch,chunk,group) counts ----------------
__global__ __launch_bounds__(256) void k_count(const int* __restrict__ vr,
                                               unsigned* __restrict__ cnt){
  __shared__ unsigned scnt[NG];
  const int t = threadIdx.x;
  scnt[t] = 0u;
  __syncthreads();

  const int b = blockIdx.x / NC;
  const int c = blockIdx.x % NC;
  const size_t base = (size_t)b*NN + (size_t)c*CH;
  const int4* v4 = (const int4*)(vr + base);

#pragma unroll
  for (int i = 0; i < CH/1024; i++){
    int4 v = v4[i*256 + t];
    atomicAdd(&scnt[v.x], 1u);
    atomicAdd(&scnt[v.y], 1u);
    atomicAdd(&scnt[v.z], 1u);
    atomicAdd(&scnt[v.w], 1u);
  }
  __syncthreads();
  cnt[(size_t)(b*NC + c)*NG + t] = scnt[t];
}

// ---- Pass 2: cnt (RO) -> off (WO) absolute scatter offsets; group base/len ----
// Separate arrays: no aliasing, so the loads pipeline instead of serializing
// against the stores.
__global__ __launch_bounds__(256) void k_offsets(const unsigned* __restrict__ cnt,
                                                 unsigned* __restrict__ off,
                                                 unsigned* __restrict__ grpbase,
                                                 unsigned* __restrict__ grplen){
  const int b = blockIdx.x;
  const int g = threadIdx.x;

  unsigned tot = 0;
  for (int c0 = 0; c0 < NC; c0 += 8){
    unsigned v0 = cnt[(size_t)(b*NC + c0 + 0)*NG + g];
    unsigned v1 = cnt[(size_t)(b*NC + c0 + 1)*NG + g];
    unsigned v2 = cnt[(size_t)(b*NC + c0 + 2)*NG + g];
    unsigned v3 = cnt[(size_t)(b*NC + c0 + 3)*NG + g];
    unsigned v4 = cnt[(size_t)(b*NC + c0 + 4)*NG + g];
    unsigned v5 = cnt[(size_t)(b*NC + c0 + 5)*NG + g];
    unsigned v6 = cnt[(size_t)(b*NC + c0 + 6)*NG + g];
    unsigned v7 = cnt[(size_t)(b*NC + c0 + 7)*NG + g];
    tot += v0 + v1 + v2 + v3 + v4 + v5 + v6 + v7;
  }

  __shared__ unsigned ss[NG];
  ss[g] = tot; __syncthreads();
  for (int d = 1; d < NG; d <<= 1){
    unsigned x = (g >= d) ? ss[g - d] : 0u;
    __syncthreads();
    ss[g] += x;
    __syncthreads();
  }
  unsigned base = ss[g] - tot;   // exclusive prefix over groups

  unsigned run = base;
  for (int c0 = 0; c0 < NC; c0 += 8){
    unsigned v[8];
#pragma unroll
    for (int j = 0; j < 8; j++) v[j] = cnt[(size_t)(b*NC + c0 + j)*NG + g];
#pragma unroll
    for (int j = 0; j < 8; j++){
      off[(size_t)(b*NC + c0 + j)*NG + g] = run;
      run += v[j];
    }
  }
  grpbase[b*NG + g] = base;
  grplen [b*NG + g] = tot;
}

// ---- Pass 3: LDS-staged stable sort of each chunk + coalesced flush ----
// Stability: waves own contiguous sub-chunks in wave-index order; per-wave
// running counters seeded with cross-wave prefix -> global element order kept
// bit-exactly (the fp32 sum chain downstream depends on it).
// LDS = 18 KB -> 8 blocks/CU (full 32 waves/CU).
__global__ __launch_bounds__(256) void k_scatter(const float* __restrict__ pr,
                                                 const int* __restrict__ vr,
                                                 const unsigned* __restrict__ off,
                                                 float* __restrict__ sorted){
  __shared__ float vbuf[CH];            // 8 KB sorted values
  __shared__ unsigned graw32[CH/4];     // 2 KB raw group ids (packed u8x4, elem order)
  __shared__ unsigned char gbuf[CH];    // 2 KB group id per sorted slot
  __shared__ unsigned wcnt[4][NG];      // per-wave histogram -> running counters
  __shared__ unsigned bias[NG];         // global_dest - local_base per group
  __shared__ unsigned ss[NG];           // scan scratch
  const int t    = threadIdx.x;
  const int lane = t & 63;
  const int w    = t >> 6;
  const int b = blockIdx.x / NC;
  const int c = blockIdx.x % NC;
  const size_t base = (size_t)b*NN + (size_t)c*CH;

#pragma unroll
  for (int k = 0; k < 4; k++) wcnt[k][t] = 0u;
  __syncthreads();

  // phase 1: per-wave histogram over its sub-chunk + stage packed group ids
  {
    const int4* v4 = (const int4*)(vr + base + (size_t)w*SC);
#pragma unroll
    for (int i = 0; i < SC/256; i++){      // 2 iters
      int4 v = v4[i*64 + lane];
      atomicAdd(&wcnt[w][v.x], 1u);
      atomicAdd(&wcnt[w][v.y], 1u);
      atomicAdd(&wcnt[w][v.z], 1u);
      atomicAdd(&wcnt[w][v.w], 1u);
      graw32[w*(SC/4) + i*64 + lane] =
        (unsigned)v.x | ((unsigned)v.y << 8) | ((unsigned)v.z << 16) | ((unsigned)v.w << 24);
    }
  }
  __syncthreads();

  // phase 2: local offsets (thread t == group id)
  {
    unsigned c0 = wcnt[0][t], c1 = wcnt[1][t], c2 = wcnt[2][t], c3 = wcnt[3][t];
    unsigned tot = c0 + c1 + c2 + c3;
    ss[t] = tot; __syncthreads();
    for (int d = 1; d < NG; d <<= 1){
      unsigned v = (t >= d) ? ss[t - d] : 0u;
      __syncthreads();
      ss[t] += v;
      __syncthreads();
    }
    unsigned lb = ss[t] - tot;              // local exclusive prefix over groups
    wcnt[0][t] = lb;
    wcnt[1][t] = lb + c0;
    wcnt[2][t] = lb + c0 + c1;
    wcnt[3][t] = lb + c0 + c1 + c2;
    bias[t] = off[(size_t)(b*NC + c)*NG + t] - lb;
  }
  __syncthreads();

  // phase 3: stable scatter into LDS (per wave, element order; g fed from LDS)
  {
    const unsigned long long below = (lane == 0) ? 0ull : ((1ull << lane) - 1ull);
    const float* psrc = pr + base + (size_t)w*SC;
    const int shft = (lane & 3) * 8;
    for (int s = 0; s < SC/64; s++){       // 8 stripes
      float p = psrc[s*64 + lane];
      // same-word broadcast read: 4 lanes share one dword, free on LDS
      unsigned packed = graw32[w*(SC/4) + s*16 + (lane >> 2)];
      int g = (int)((packed >> shft) & 255u);
      unsigned long long mask = ~0ull;
#pragma unroll
      for (int bit = 0; bit < 8; bit++){
        int bv = (g >> bit) & 1;
        unsigned long long bal = __ballot(bv);
        mask &= bv ? bal : ~bal;
      }
      int rank = __popcll(mask & below);
      unsigned old = wcnt[w][g];                 // all lanes read pre-update value
      if (rank == 0) wcnt[w][g] = old + (unsigned)__popcll(mask);
      vbuf[old + (unsigned)rank] = p;
      gbuf[old + (unsigned)rank] = (unsigned char)g;
    }
  }
  __syncthreads();

  // phase 4: coalesced flush (consecutive p -> consecutive dest within group runs)
  {
    float* dst = sorted + (size_t)b*NN;
    const unsigned* gbuf32 = (const unsigned*)gbuf;
#pragma unroll
    for (int k = 0; k < CH/256; k++){      // 8 iters
      int p = k*256 + t;
      unsigned packed = gbuf32[p >> 2];    // broadcast within 4 threads
      unsigned g = (packed >> ((p & 3) * 8)) & 255u;
      dst[bias[g] + (unsigned)p] = vbuf[p];
    }
  }
}

// ---- Pass 4: one LANE per (batch,group); 4-deep 16-elem register pipeline
//      hides load latency; fp32 add chain stays in exact element order. ----
__global__ __launch_bounds__(32) void k_sum(const float* __restrict__ sorted,
                                            const unsigned* __restrict__ grpbase,
                                            const unsigned* __restrict__ grplen,
                                            float* __restrict__ gsum,
                                            float* __restrict__ gmn,
                                            float* __restrict__ gmx){
  const int lane = threadIdx.x;                  // 0..31
  const int b = blockIdx.x >> 3;                 // 8 blocks per batch
  const int g = ((blockIdx.x & 7) << 5) + lane;  // one group per lane

  const unsigned base = grpbase[b*NG + g];
  const unsigned len  = grplen [b*NG + g];
  const float* sp = sorted + (size_t)b*NN + base;

  float s = 0.0f, mn = INFINITY, mx = -INFINITY;
  float b0[16], b1[16], b2[16], b3[16];
  const unsigned nfull = len >> 4;

#define LOADV(DST, K) { _Pragma("unroll") for (int j = 0; j < 16; j++) DST[j] = sp[(K)*16u + j]; }
#define CONSV(Q)      { _Pragma("unroll") for (int j = 0; j < 16; j++){ float v = Q[j]; \
                        s = __fadd_rn(s, v); mn = fminf(mn, v); mx = fmaxf(mx, v); } }

  if (nfull > 0) LOADV(b0, 0)
  if (nfull > 1) LOADV(b1, 1)
  if (nfull > 2) LOADV(b2, 2)
  if (nfull > 3) LOADV(b3, 3)
  unsigned k = 0;
  for (; k + 4 <= nfull; k += 4){
    CONSV(b0) if (k + 4 < nfull) LOADV(b0, k + 4)
    CONSV(b1) if (k + 5 < nfull) LOADV(b1, k + 5)
    CONSV(b2) if (k + 6 < nfull) LOADV(b2, k + 6)
    CONSV(b3) if (k + 7 < nfull) LOADV(b3, k + 7)
  }
  {
    unsigned r = nfull - k;        // 0..3 remaining full batches, in b0..b2
    if (r > 0) CONSV(b0)
    if (r > 1) CONSV(b1)
    if (r > 2) CONSV(b2)
  }
  for (unsigned i = nfull << 4; i < len; i++){
    float v = sp[i];
    s = __fadd_rn(s, v);
    mn = fminf(mn, v); mx = fmaxf(mx, v);
  }
#undef LOADV
#undef CONSV

  gsum[b*NG + g] = s;
  gmn [b*NG + g] = mn;
  gmx [b*NG + g] = mx;
}

// ---- Pass 5: per-batch group pipeline (blend, stable rank, f0/f1, no_scale) ----
// params layout: SoA, params[(b*4 + comp)*NG + g]
__global__ __launch_bounds__(256) void k_pipeline(const float* __restrict__ gsum,
                                                  const float* __restrict__ gmn,
                                                  const float* __restrict__ gmx,
                                                  const float* __restrict__ inp_means,
                                                  const float* __restrict__ Wv,
                                                  float* __restrict__ params){
  const int b = blockIdx.x;
  const int g = threadIdx.x;
  __shared__ float vm[NG];
  __shared__ float vs[NG];

  const float s   = gsum[b*NG + g];   // empty group: len==0 -> s==0 (matches where(vany,...))
  const float mnf = gmn [b*NG + g];
  const float mxf = gmx [b*NG + g];
  const float W0 = Wv[0], W1 = Wv[1];
  float mean = __fdiv_rn(__fadd_rn(__fmul_rn(inp_means[b*NG + g], W0),
                                   __fmul_rn(s, W1)),
                         __fadd_rn(W0, W1));
  vm[g] = mean;
  __syncthreads();

  // stable rank == position after stable argsort
  int r = 0;
  for (int j = 0; j < NG; j++){
    float x = vm[j];
    r += (x < mean) || (x == mean && j < g);
  }
  vs[r] = mean;
  __syncthreads();

  float c0 = (r == 0)    ? vs[0]                     : vs[r-1];
  float c1 = vs[r];
  float c2 = (r == NG-1) ? __fmul_rn(vs[NG-1], 2.0f) : vs[r+1];
  float f0 = __fdiv_rn(__fadd_rn(c0, c1), 1.999f);
  float f1 = __fdiv_rn(__fadd_rn(c1, c2), 2.001f);

  bool ns = (mnf == mxf);
  params[(b*4 + 0)*NG + g] = ns ? 0.0f : mnf;                  // vmin_use
  params[(b*4 + 1)*NG + g] = ns ? 1.0f : __fsub_rn(mxf, mnf);  // range_use
  params[(b*4 + 2)*NG + g] = ns ? 1.0f : __fsub_rn(f1, f0);    // (f1-f0)_use
  params[(b*4 + 3)*NG + g] = ns ? 0.0f : f0;                   // f0_use
}

// ---- Pass 6: per-element apply, fp32 replicating reference op order ----
static __device__ __forceinline__ float apply_one(float p, int g,
                                                  const float* __restrict__ sp0,
                                                  const float* __restrict__ sp1,
                                                  const float* __restrict__ sp2,
                                                  const float* __restrict__ sp3){
  float t1  = __fsub_rn(p, sp0[g]);
  float t3  = __fdiv_rn(t1, sp1[g]);
  float t5  = __fmul_rn(t3, sp2[g]);
  float tmp = __fadd_rn(t5, sp3[g]);
  bool bad = __builtin_isnan(tmp) || (tmp == 0.0f);
  float s = __fdiv_rn(p, bad ? 1.0f : tmp);
  bool bad2 = bad || __builtin_isnan(s) || __builtin_isinf(s);
  float sc = bad2 ? 0.0f : s;
  return __fmul_rn(p, sc);
}

__global__ __launch_bounds__(256) void k_apply(const float* __restrict__ pr,
                                               const int* __restrict__ vr,
                                               const float* __restrict__ params,
                                               float* __restrict__ out){
  __shared__ float sp0[NG], sp1[NG], sp2[NG], sp3[NG];
  const int t = threadIdx.x;
  const int b = blockIdx.x / CD;
  const int c = blockIdx.x % CD;

  sp0[t] = params[(b*4 + 0)*NG + t];
  sp1[t] = params[(b*4 + 1)*NG + t];
  sp2[t] = params[(b*4 + 2)*NG + t];
  sp3[t] = params[(b*4 + 3)*NG + t];
  __syncthreads();

  const size_t base = (size_t)b*NN + (size_t)c*ELD;
  const float4* p4 = (const float4*)(pr + base);
  const int4*  v4 = (const int4*)(vr + base);
  float4* o4 = (float4*)(out + base);

#pragma unroll
  for (int i = 0; i < ELD/1024; i++){
    float4 p = p4[i*256 + t];
    int4   v = v4[i*256 + t];
    float4 r;
    r.x = apply_one(p.x, v.x, sp0, sp1, sp2, sp3);
    r.y = apply_one(p.y, v.y, sp0, sp1, sp2, sp3);
    r.z = apply_one(p.z, v.z, sp0, sp1, sp2, sp3);
    r.w = apply_one(p.w, v.w, sp0, sp1, sp2, sp3);
    o4[i*256 + t] = r;
  }
}

extern "C" void kernel_launch(void* const* d_in, const int* in_sizes, int n_in,
                              void* d_out, int out_size, void* d_ws, size_t ws_size,
                              hipStream_t stream){
  const float* pr        = (const float*)d_in[0];
  const float* inp_means = (const float*)d_in[1];
  const int*   vr        = (const int*)d_in[2];
  const float* W         = (const float*)d_in[3];
  float* out = (float*)d_out;

  char* ws = (char*)d_ws;
  size_t o = 0;
  unsigned* cnt     = (unsigned*)(ws + o); o += (size_t)NB*NC*NG*4;  // 4 MB
  unsigned* off     = (unsigned*)(ws + o); o += (size_t)NB*NC*NG*4;  // 4 MB
  unsigned* grpbase = (unsigned*)(ws + o); o += (size_t)NB*NG*4;     // 32 KB
  unsigned* grplen  = (unsigned*)(ws + o); o += (size_t)NB*NG*4;
  float*    gsum    = (float*)   (ws + o); o += (size_t)NB*NG*4;
  float*    gmn     = (float*)   (ws + o); o += (size_t)NB*NG*4;
  float*    gmx     = (float*)   (ws + o); o += (size_t)NB*NG*4;
  float*    params  = (float*)   (ws + o); o += (size_t)NB*NG*16;    // 128 KB (SoA)
  // sorted values live in d_out (fully overwritten by k_apply afterwards)
  float* sorted = out;

  k_count   <<<NB*NC, 256, 0, stream>>>(vr, cnt);
  k_offsets <<<NB,     NG, 0, stream>>>(cnt, off, grpbase, grplen);
  k_scatter <<<NB*NC, 256, 0, stream>>>(pr, vr, off, sorted);
  k_sum     <<<NB*8,   32, 0, stream>>>(sorted, grpbase, grplen, gsum, gmn, gmx);
  k_pipeline<<<NB,     NG, 0, stream>>>(gsum, gmn, gmx, inp_means, W, params);
  k_apply   <<<NB*CD, 256, 0, stream>>>(pr, vr, params, out);
}

// Round 9
// 175.203 us; speedup vs baseline: 1.0562x; 1.0562x over previous
//
#include <hip/hip_runtime.h>
#include <math.h>

#define NB 32
#define NN 262144
#define NG 256
#define NC 64             // chunks per batch (sort passes)
#define CH (NN/NC)        // 4096 elements per chunk
#define SC (CH/4)         // 1024 elements per wave (4 waves/block)
#define CD 64             // chunks per batch, apply pass
#define ELD (NN/CD)       // 4096 elements per apply block

// ---- Pass 1: per-(batch,chunk,group) counts + packed u8 gid emission ----
__global__ __launch_bounds__(256) void k_count(const int* __restrict__ vr,
                                               unsigned* __restrict__ cnt,
                                               unsigned* __restrict__ gid32){
  __shared__ unsigned scnt[NG];
  const int t = threadIdx.x;
  scnt[t] = 0u;
  __syncthreads();

  const int b = blockIdx.x / NC;
  const int c = blockIdx.x % NC;
  const size_t base = (size_t)b*NN + (size_t)c*CH;
  const int4* v4 = (const int4*)(vr + base);

#pragma unroll
  for (int i = 0; i < CH/1024; i++){     // 4 iters
    int4 v = v4[i*256 + t];
    atomicAdd(&scnt[v.x], 1u);
    atomicAdd(&scnt[v.y], 1u);
    atomicAdd(&scnt[v.z], 1u);
    atomicAdd(&scnt[v.w], 1u);
    gid32[(base >> 2) + i*256 + t] =
      (unsigned)v.x | ((unsigned)v.y << 8) | ((unsigned)v.z << 16) | ((unsigned)v.w << 24);
  }
  __syncthreads();
  cnt[(size_t)(b*NC + c)*NG + t] = scnt[t];
}

// ---- Pass 2: rewrite cnt in place into absolute scatter offsets (loads all
//      hoisted to regs first, so they pipeline); emit group base/len ----
__global__ __launch_bounds__(256) void k_offsets(unsigned* __restrict__ cnt,
                                                 unsigned* __restrict__ grpbase,
                                                 unsigned* __restrict__ grplen){
  const int b = blockIdx.x;
  const int g = threadIdx.x;

  unsigned v[NC];
#pragma unroll
  for (int c = 0; c < NC; c++) v[c] = cnt[(size_t)(b*NC + c)*NG + g];
  unsigned tot = 0;
#pragma unroll
  for (int c = 0; c < NC; c++) tot += v[c];

  __shared__ unsigned ss[NG];
  ss[g] = tot; __syncthreads();
  for (int d = 1; d < NG; d <<= 1){
    unsigned x = (g >= d) ? ss[g - d] : 0u;
    __syncthreads();
    ss[g] += x;
    __syncthreads();
  }
  unsigned base = ss[g] - tot;   // exclusive prefix over groups

  unsigned run = base;
#pragma unroll
  for (int c = 0; c < NC; c++){
    cnt[(size_t)(b*NC + c)*NG + g] = run;
    run += v[c];
  }
  grpbase[b*NG + g] = base;
  grplen [b*NG + g] = tot;
}

// ---- Pass 3: LDS-staged stable sort of each chunk + coalesced flush ----
// Stability: waves own contiguous sub-chunks in wave-index order; per-wave
// running counters seeded with cross-wave prefix -> global element order kept
// bit-exactly (the fp32 sum chain downstream depends on it).
__global__ __launch_bounds__(256) void k_scatter(const float* __restrict__ pr,
                                                 const unsigned* __restrict__ gid32,
                                                 const unsigned* __restrict__ off,
                                                 float* __restrict__ sorted){
  __shared__ float vbuf[CH];            // 16 KB sorted values
  __shared__ unsigned graw32[CH/4];     // 4 KB raw gids (packed u8x4, elem order)
  __shared__ unsigned char gbuf[CH];    // 4 KB gid per sorted slot
  __shared__ unsigned wcnt[4][NG];      // per-wave histogram -> running counters
  __shared__ unsigned bias[NG];         // global_dest - local_base per group
  __shared__ unsigned ss[NG];           // scan scratch
  const int t    = threadIdx.x;
  const int lane = t & 63;
  const int w    = t >> 6;
  const int b = blockIdx.x / NC;
  const int c = blockIdx.x % NC;
  const size_t base = (size_t)b*NN + (size_t)c*CH;

#pragma unroll
  for (int k = 0; k < 4; k++) wcnt[k][t] = 0u;
  __syncthreads();

  // phase 1: one int4 of packed gids per lane -> LDS stage + histogram
  {
    const uint4* g4 = (const uint4*)(gid32 + (base >> 2));
    uint4 pk = g4[w*64 + lane];          // 16 gids, element order
    ((uint4*)graw32)[w*64 + lane] = pk;  // ds_write_b128, order preserved
#define HIST4(P) { atomicAdd(&wcnt[w][(P) & 255u], 1u); \
                   atomicAdd(&wcnt[w][((P) >> 8) & 255u], 1u); \
                   atomicAdd(&wcnt[w][((P) >> 16) & 255u], 1u); \
                   atomicAdd(&wcnt[w][(P) >> 24], 1u); }
    HIST4(pk.x) HIST4(pk.y) HIST4(pk.z) HIST4(pk.w)
#undef HIST4
  }
  __syncthreads();

  // phase 2: local offsets (thread t == group id)
  {
    unsigned c0 = wcnt[0][t], c1 = wcnt[1][t], c2 = wcnt[2][t], c3 = wcnt[3][t];
    unsigned tot = c0 + c1 + c2 + c3;
    ss[t] = tot; __syncthreads();
    for (int d = 1; d < NG; d <<= 1){
      unsigned v = (t >= d) ? ss[t - d] : 0u;
      __syncthreads();
      ss[t] += v;
      __syncthreads();
    }
    unsigned lb = ss[t] - tot;              // local exclusive prefix over groups
    wcnt[0][t] = lb;
    wcnt[1][t] = lb + c0;
    wcnt[2][t] = lb + c0 + c1;
    wcnt[3][t] = lb + c0 + c1 + c2;
    bias[t] = off[(size_t)(b*NC + c)*NG + t] - lb;
  }
  __syncthreads();

  // phase 3: stable scatter into LDS (per wave, element order; g fed from LDS)
  {
    const unsigned long long below = (lane == 0) ? 0ull : ((1ull << lane) - 1ull);
    const float* psrc = pr + base + (size_t)w*SC;
    const int shft = (lane & 3) * 8;
    for (int s = 0; s < SC/64; s++){       // 16 stripes
      float p = psrc[s*64 + lane];
      // same-word broadcast read: 4 lanes share one dword, free on LDS
      unsigned packed = graw32[w*(SC/4) + s*16 + (lane >> 2)];
      int g = (int)((packed >> shft) & 255u);
      unsigned long long mask = ~0ull;
#pragma unroll
      for (int bit = 0; bit < 8; bit++){
        int bv = (g >> bit) & 1;
        unsigned long long bal = __ballot(bv);
        mask &= bv ? bal : ~bal;
      }
      int rank = __popcll(mask & below);
      unsigned old = wcnt[w][g];                 // all lanes read pre-update value
      if (rank == 0) wcnt[w][g] = old + (unsigned)__popcll(mask);
      vbuf[old + (unsigned)rank] = p;
      gbuf[old + (unsigned)rank] = (unsigned char)g;
    }
  }
  __syncthreads();

  // phase 4: coalesced flush (consecutive p -> consecutive dest within group runs)
  {
    float* dst = sorted + (size_t)b*NN;
    const unsigned* gbuf32 = (const unsigned*)gbuf;
#pragma unroll
    for (int k = 0; k < CH/256; k++){      // 16 iters
      int p = k*256 + t;
      unsigned packed = gbuf32[p >> 2];    // broadcast within 4 threads
      unsigned g = (packed >> ((p & 3) * 8)) & 255u;
      dst[bias[g] + (unsigned)p] = vbuf[p];
    }
  }
}

// ---- Pass 4: one LANE per (batch,group); float4 loads, 8-deep register
//      pipeline. Scalar head to 16B alignment + scalar tail keep the fp32 add
//      chain in exact element order (bit-exact). ----
__global__ __launch_bounds__(32) void k_sum(const float* __restrict__ sorted,
                                            const unsigned* __restrict__ grpbase,
                                            const unsigned* __restrict__ grplen,
                                            float* __restrict__ gsum,
                                            float* __restrict__ gmn,
                                            float* __restrict__ gmx){
  const int lane = threadIdx.x;                  // 0..31
  const int b = blockIdx.x >> 3;                 // 8 blocks per batch
  const int g = ((blockIdx.x & 7) << 5) + lane;  // one group per lane

  const unsigned base = grpbase[b*NG + g];
  const unsigned len  = grplen [b*NG + g];
  const float* sp = sorted + (size_t)b*NN + base;

  float s = 0.0f, mn = INFINITY, mx = -INFINITY;

  // scalar head to 16B alignment (element order preserved)
  unsigned head = (4u - ((unsigned)(((size_t)sp) >> 2) & 3u)) & 3u;
  if (head > len) head = len;
  for (unsigned i = 0; i < head; i++){
    float v = sp[i];
    s = __fadd_rn(s, v); mn = fminf(mn, v); mx = fmaxf(mx, v);
  }
  const float4* f4 = (const float4*)(sp + head);
  const unsigned rem   = len - head;
  const unsigned nfull = rem >> 4;               // 16-elem batches (4 x float4)

  float4 b0[4], b1[4], b2[4], b3[4], b4[4], b5[4], b6[4], b7[4];
#define LOADV(D, K) { D[0]=f4[(K)*4+0]; D[1]=f4[(K)*4+1]; D[2]=f4[(K)*4+2]; D[3]=f4[(K)*4+3]; }
#define CONS1(V)    { s=__fadd_rn(s,(V)); mn=fminf(mn,(V)); mx=fmaxf(mx,(V)); }
#define CONSV(D)    { _Pragma("unroll") for (int j = 0; j < 4; j++){ float4 q = D[j]; \
                      CONS1(q.x) CONS1(q.y) CONS1(q.z) CONS1(q.w) } }

  if (nfull > 0) LOADV(b0, 0)
  if (nfull > 1) LOADV(b1, 1)
  if (nfull > 2) LOADV(b2, 2)
  if (nfull > 3) LOADV(b3, 3)
  if (nfull > 4) LOADV(b4, 4)
  if (nfull > 5) LOADV(b5, 5)
  if (nfull > 6) LOADV(b6, 6)
  if (nfull > 7) LOADV(b7, 7)
  unsigned k = 0;
  for (; k + 8 <= nfull; k += 8){
    CONSV(b0) if (k +  8 < nfull) LOADV(b0, k +  8)
    CONSV(b1) if (k +  9 < nfull) LOADV(b1, k +  9)
    CONSV(b2) if (k + 10 < nfull) LOADV(b2, k + 10)
    CONSV(b3) if (k + 11 < nfull) LOADV(b3, k + 11)
    CONSV(b4) if (k + 12 < nfull) LOADV(b4, k + 12)
    CONSV(b5) if (k + 13 < nfull) LOADV(b5, k + 13)
    CONSV(b6) if (k + 14 < nfull) LOADV(b6, k + 14)
    CONSV(b7) if (k + 15 < nfull) LOADV(b7, k + 15)
  }
  {
    unsigned r = nfull - k;        // 0..7 remaining full batches in b0..b6
    if (r > 0) CONSV(b0)
    if (r > 1) CONSV(b1)
    if (r > 2) CONSV(b2)
    if (r > 3) CONSV(b3)
    if (r > 4) CONSV(b4)
    if (r > 5) CONSV(b5)
    if (r > 6) CONSV(b6)
  }
  for (unsigned i = head + (nfull << 4); i < len; i++){
    float v = sp[i];
    s = __fadd_rn(s, v); mn = fminf(mn, v); mx = fmaxf(mx, v);
  }
#undef LOADV
#undef CONS1
#undef CONSV

  gsum[b*NG + g] = s;
  gmn [b*NG + g] = mn;
  gmx [b*NG + g] = mx;
}

// ---- Pass 5: per-batch group pipeline (blend, stable rank, f0/f1, no_scale) ----
// params layout: SoA, params[(b*4 + comp)*NG + g]
__global__ __launch_bounds__(256) void k_pipeline(const float* __restrict__ gsum,
                                                  const float* __restrict__ gmn,
                                                  const float* __restrict__ gmx,
                                                  const float* __restrict__ inp_means,
                                                  const float* __restrict__ Wv,
                                                  float* __restrict__ params){
  const int b = blockIdx.x;
  const int g = threadIdx.x;
  __shared__ float vm[NG];
  __shared__ float vs[NG];

  const float s   = gsum[b*NG + g];   // empty group: len==0 -> s==0 (matches where(vany,...))
  const float mnf = gmn [b*NG + g];
  const float mxf = gmx [b*NG + g];
  const float W0 = Wv[0], W1 = Wv[1];
  float mean = __fdiv_rn(__fadd_rn(__fmul_rn(inp_means[b*NG + g], W0),
                                   __fmul_rn(s, W1)),
                         __fadd_rn(W0, W1));
  vm[g] = mean;
  __syncthreads();

  // stable rank == position after stable argsort
  int r = 0;
  for (int j = 0; j < NG; j++){
    float x = vm[j];
    r += (x < mean) || (x == mean && j < g);
  }
  vs[r] = mean;
  __syncthreads();

  float c0 = (r == 0)    ? vs[0]                     : vs[r-1];
  float c1 = vs[r];
  float c2 = (r == NG-1) ? __fmul_rn(vs[NG-1], 2.0f) : vs[r+1];
  float f0 = __fdiv_rn(__fadd_rn(c0, c1), 1.999f);
  float f1 = __fdiv_rn(__fadd_rn(c1, c2), 2.001f);

  bool ns = (mnf == mxf);
  params[(b*4 + 0)*NG + g] = ns ? 0.0f : mnf;                  // vmin_use
  params[(b*4 + 1)*NG + g] = ns ? 1.0f : __fsub_rn(mxf, mnf);  // range_use
  params[(b*4 + 2)*NG + g] = ns ? 1.0f : __fsub_rn(f1, f0);    // (f1-f0)_use
  params[(b*4 + 3)*NG + g] = ns ? 0.0f : f0;                   // f0_use
}

// ---- Pass 6: per-element apply, fp32 replicating reference op order ----
static __device__ __forceinline__ float apply_one(float p, unsigned g,
                                                  const float* __restrict__ sp0,
                                                  const float* __restrict__ sp1,
                                                  const float* __restrict__ sp2,
                                                  const float* __restrict__ sp3){
  float t1  = __fsub_rn(p, sp0[g]);
  float t3  = __fdiv_rn(t1, sp1[g]);
  float t5  = __fmul_rn(t3, sp2[g]);
  float tmp = __fadd_rn(t5, sp3[g]);
  bool bad = __builtin_isnan(tmp) || (tmp == 0.0f);
  float s = __fdiv_rn(p, bad ? 1.0f : tmp);
  bool bad2 = bad || __builtin_isnan(s) || __builtin_isinf(s);
  float sc = bad2 ? 0.0f : s;
  return __fmul_rn(p, sc);
}

__global__ __launch_bounds__(256) void k_apply(const float* __restrict__ pr,
                                               const unsigned* __restrict__ gid32,
                                               const float* __restrict__ params,
                                               float* __restrict__ out){
  __shared__ float sp0[NG], sp1[NG], sp2[NG], sp3[NG];
  const int t = threadIdx.x;
  const int b = blockIdx.x / CD;
  const int c = blockIdx.x % CD;

  sp0[t] = params[(b*4 + 0)*NG + t];
  sp1[t] = params[(b*4 + 1)*NG + t];
  sp2[t] = params[(b*4 + 2)*NG + t];
  sp3[t] = params[(b*4 + 3)*NG + t];
  __syncthreads();

  const size_t base = (size_t)b*NN + (size_t)c*ELD;
  const float4* p4 = (const float4*)(pr + base);
  float4* o4 = (float4*)(out + base);

#pragma unroll
  for (int i = 0; i < ELD/1024; i++){
    float4 p = p4[i*256 + t];
    unsigned pk = gid32[(base >> 2) + i*256 + t];
    float4 r;
    r.x = apply_one(p.x,  pk        & 255u, sp0, sp1, sp2, sp3);
    r.y = apply_one(p.y, (pk >>  8) & 255u, sp0, sp1, sp2, sp3);
    r.z = apply_one(p.z, (pk >> 16) & 255u, sp0, sp1, sp2, sp3);
    r.w = apply_one(p.w,  pk >> 24,         sp0, sp1, sp2, sp3);
    o4[i*256 + t] = r;
  }
}

extern "C" void kernel_launch(void* const* d_in, const int* in_sizes, int n_in,
                              void* d_out, int out_size, void* d_ws, size_t ws_size,
                              hipStream_t stream){
  const float* pr        = (const float*)d_in[0];
  const float* inp_means = (const float*)d_in[1];
  const int*   vr        = (const int*)d_in[2];
  const float* W         = (const float*)d_in[3];
  float* out = (float*)d_out;

  char* ws = (char*)d_ws;
  size_t o = 0;
  unsigned* cnt     = (unsigned*)(ws + o); o += (size_t)NB*NC*NG*4;  // 2 MB
  unsigned* gid32   = (unsigned*)(ws + o); o += (size_t)NB*NN;       // 8 MB packed u8 gids
  unsigned* grpbase = (unsigned*)(ws + o); o += (size_t)NB*NG*4;     // 32 KB
  unsigned* grplen  = (unsigned*)(ws + o); o += (size_t)NB*NG*4;
  float*    gsum    = (float*)   (ws + o); o += (size_t)NB*NG*4;
  float*    gmn     = (float*)   (ws + o); o += (size_t)NB*NG*4;
  float*    gmx     = (float*)   (ws + o); o += (size_t)NB*NG*4;
  float*    params  = (float*)   (ws + o); o += (size_t)NB*NG*16;    // 128 KB (SoA)
  // sorted values live in d_out (fully overwritten by k_apply afterwards)
  float* sorted = out;

  k_count   <<<NB*NC, 256, 0, stream>>>(vr, cnt, gid32);
  k_offsets <<<NB,     NG, 0, stream>>>(cnt, grpbase, grplen);
  k_scatter <<<NB*NC, 256, 0, stream>>>(pr, gid32, cnt, sorted);
  k_sum     <<<NB*8,   32, 0, stream>>>(sorted, grpbase, grplen, gsum, gmn, gmx);
  k_pipeline<<<NB,     NG, 0, stream>>>(gsum, gmn, gmx, inp_means, W, params);
  k_apply   <<<NB*CD, 256, 0, stream>>>(pr, gid32, params, out);
}